// Round 13
// baseline (64.762 us; speedup 1.0000x reference)
//
#include <hip/hip_runtime.h>
#include <math.h>

// Router: B=4, S=8192, D=1024, E=64, TOP_K=2 (all fp32)
// Output layout (fp32, concatenated flat):
//   [0,       65536)   top_k_probs   [4,8192,2]
//   [65536,   131072)  selected_experts (as float) [4,8192,2]
//   [131072,  2228224) router_logits [4,8192,64]
//
// R13 = R12 (fp32-exact 3-level bf16 split on mfma_f32_32x32x16_bf16)
// + RACE FIX: R12's combine overlay (33.7 KB, stride-33 floats for 256
// lane-slots) overflowed buf0 (24 KB) into buf1 while kh=0 waves were
// still reading buf1 in step 15 (no barrier after the last MFMA step)
// -> garbage bf16 (inf/NaN encodings) into MFMA -> NaN. Fix: a single
// __syncthreads() between the main loop and the combine writes; after
// it the whole 48 KB staging region is quiescent.
//  Structure (unchanged from R12): wave = 32 tokens x 64 experts
//  (2 n-tiles of 32) x K-half; block = 8 waves (4 mg x 2 kh) = 128
//  tokens; grid 256; 2 blocks/CU; 4 waves/SIMD; 16-step ring-2 staging,
//  24 segs/step (3/wave), counted vmcnt(4) + raw barrier per step.
//  Fragments: A row=lane&31, k=(lane>>5)*8+j; B col=lane&31 (mirrored);
//  C/D col=lane&31, row=(reg&3)+8*(reg>>2)+4*(lane>>5) [m74/m101].

typedef __attribute__((ext_vector_type(8)))  short bf16x8;
typedef __attribute__((ext_vector_type(16))) float f32x16;

static constexpr int TOKENS = 32768;
static constexpr int DDIM   = 1024;
static constexpr int NEXP   = 64;
static constexpr size_t OFF_EXP = 65536;
static constexpr size_t OFF_LOG = 131072;

// ---- W 3-level split + 32x32-B-fragment permute ----
// (e,k): nt=e>>5, col=e&31, kstep=k>>4, lane=col+32*((k>>3)&1), j=k&7
// dst (shorts) = ((kstep*2+nt)*64 + lane)*8 + j      (bijection)
__global__ void w_split3_kernel(const float* __restrict__ w,
                                short* __restrict__ w1,
                                short* __restrict__ w2,
                                short* __restrict__ w3) {
    int idx = blockIdx.x * blockDim.x + threadIdx.x;
    for (int i = idx; i < NEXP * DDIM; i += gridDim.x * blockDim.x) {
        int e = i >> 10, k = i & 1023;
        float f = w[i];
        unsigned u1 = __float_as_uint(f);
        float f1 = __uint_as_float(u1 & 0xffff0000u);
        float r1 = f - f1;
        unsigned u2 = __float_as_uint(r1);
        float f2 = __uint_as_float(u2 & 0xffff0000u);
        float r2 = r1 - f2;
        unsigned u3 = __float_as_uint(r2);
        int nt = e >> 5, col = e & 31;
        int kstep = k >> 4;
        int lane = col + 32 * ((k >> 3) & 1);
        int j = k & 7;
        size_t dst = ((size_t)(kstep * 2 + nt) * 64 + lane) * 8 + j;
        w1[dst] = (short)(u1 >> 16);
        w2[dst] = (short)(u2 >> 16);
        w3[dst] = (short)(u3 >> 16);
    }
}

__device__ inline void split8(float4 a, float4 b,
                              bf16x8& o1, bf16x8& o2, bf16x8& o3) {
    float f[8] = {a.x, a.y, a.z, a.w, b.x, b.y, b.z, b.w};
#pragma unroll
    for (int j = 0; j < 8; ++j) {
        unsigned u1 = __float_as_uint(f[j]);
        float f1 = __uint_as_float(u1 & 0xffff0000u);
        float r1 = f[j] - f1;
        unsigned u2 = __float_as_uint(r1);
        float f2 = __uint_as_float(u2 & 0xffff0000u);
        float r2 = r1 - f2;
        o1[j] = (short)(u1 >> 16);
        o2[j] = (short)(u2 >> 16);
        o3[j] = (short)(__float_as_uint(r2) >> 16);
    }
}

typedef const __attribute__((address_space(1))) unsigned int* gas1_t;
typedef __attribute__((address_space(3))) unsigned int* las3_t;
__device__ inline void stage16(const void* g, void* l) {
    __builtin_amdgcn_global_load_lds((gas1_t)(uintptr_t)g,
                                     (las3_t)(uintptr_t)l, 16, 0, 0);
}

__global__ __launch_bounds__(512, 4)
void router_mfma_kernel(const float* __restrict__ h,
                        const short* __restrict__ w1,
                        const short* __restrict__ w2,
                        const short* __restrict__ w3,
                        float* __restrict__ out) {
    // 2 staging bufs x 24 KB at smem + b*24576.
    // Buf layout: [kh][arr][q=si*2+nt] x 1KB. Combine overlay uses the
    // whole region AFTER the post-loop __syncthreads (quiescent then).
    __shared__ alignas(16) char smem[49152];
    const int tid  = threadIdx.x;
    const int lane = tid & 63;
    const int wv   = tid >> 6;          // 0..7
    const int kh   = wv & 1;            // K half (0: k<512, 1: k>=512)
    const int mg   = wv >> 1;           // M group 0..3 (32 tokens each)
    const int token0 = blockIdx.x * 128 + mg * 32;
    const int col  = lane & 31;         // A/B row/col within 32-tile
    const int hh   = lane >> 5;         // k-subgroup

    const float* ap = h + (size_t)(token0 + col) * DDIM + kh * 512 + hh * 8;

    // staging: seg = wv*3+i in [0,24); kh_s=seg/12, rem=seg%12,
    // arr=rem/4, q=rem%4 (q=si*2+nt). src advances t*4096/step.
    const short* warr[3] = {w1, w2, w3};
    const char* gsrc[3];
    int ldso[3];
#pragma unroll
    for (int i = 0; i < 3; ++i) {
        int seg = wv * 3 + i;
        int kh_s = seg / 12;
        int rem  = seg % 12;
        int arr  = rem >> 2, q = rem & 3;
        gsrc[i] = (const char*)warr[arr] + (size_t)kh_s * 65536 + q * 1024
                + lane * 16;
        ldso[i] = kh_s * 12288 + arr * 4096 + q * 1024;
    }

#define STAGE(bb, tt)                                                      \
    {                                                                      \
        _Pragma("unroll")                                                  \
        for (int i = 0; i < 3; ++i)                                        \
            stage16(gsrc[i] + (size_t)(tt) * 4096,                         \
                    smem + (bb) * 24576 + ldso[i]);                        \
    }

    f32x16 acc[2];      // [n-tile]: 32 experts each
#pragma unroll
    for (int nt = 0; nt < 2; ++nt)
#pragma unroll
        for (int q = 0; q < 16; ++q) acc[nt][q] = 0.0f;

    // A ping-pong: [slot][si][lo/hi]; static indices (full unroll).
    float4 ring[2][2][2];

    // prologue: [DMA(0)x3, A(0)x4] -> retire DMA(0): vmcnt(4)
    STAGE(0, 0);
    ring[0][0][0] = *reinterpret_cast<const float4*>(ap);
    ring[0][0][1] = *reinterpret_cast<const float4*>(ap + 4);
    ring[0][1][0] = *reinterpret_cast<const float4*>(ap + 16);
    ring[0][1][1] = *reinterpret_cast<const float4*>(ap + 20);
    asm volatile("s_waitcnt vmcnt(4)" ::: "memory");
    __builtin_amdgcn_s_barrier();

#pragma unroll
    for (int t = 0; t < 16; ++t) {
        const int b = t & 1;
        if (t + 1 < 16) {
            STAGE(b ^ 1, t + 1);                    // DMA(t+1) x3
            ring[b ^ 1][0][0] =
                *reinterpret_cast<const float4*>(ap + (t + 1) * 32);
            ring[b ^ 1][0][1] =
                *reinterpret_cast<const float4*>(ap + (t + 1) * 32 + 4);
            ring[b ^ 1][1][0] =
                *reinterpret_cast<const float4*>(ap + (t + 1) * 32 + 16);
            ring[b ^ 1][1][1] =
                *reinterpret_cast<const float4*>(ap + (t + 1) * 32 + 20);
        }

        bf16x8 A1[2], A2[2], A3[2];
        split8(ring[b][0][0], ring[b][0][1], A1[0], A2[0], A3[0]);  // si=0
        split8(ring[b][1][0], ring[b][1][1], A1[1], A2[1], A3[1]);  // si=1

        const char* wb = smem + b * 24576 + kh * 12288 + lane * 16;
#pragma unroll
        for (int si = 0; si < 2; ++si)
#pragma unroll
            for (int nt = 0; nt < 2; ++nt) {
                const int q = si * 2 + nt;
                bf16x8 W1v = *reinterpret_cast<const bf16x8*>(wb + q * 1024);
                bf16x8 W2v = *reinterpret_cast<const bf16x8*>(wb + q * 1024 + 4096);
                bf16x8 W3v = *reinterpret_cast<const bf16x8*>(wb + q * 1024 + 8192);
                f32x16 t2 = acc[nt];
                t2 = __builtin_amdgcn_mfma_f32_32x32x16_bf16(A3[si], W1v, t2, 0, 0, 0);
                t2 = __builtin_amdgcn_mfma_f32_32x32x16_bf16(A1[si], W3v, t2, 0, 0, 0);
                t2 = __builtin_amdgcn_mfma_f32_32x32x16_bf16(A2[si], W2v, t2, 0, 0, 0);
                t2 = __builtin_amdgcn_mfma_f32_32x32x16_bf16(A2[si], W1v, t2, 0, 0, 0);
                t2 = __builtin_amdgcn_mfma_f32_32x32x16_bf16(A1[si], W2v, t2, 0, 0, 0);
                t2 = __builtin_amdgcn_mfma_f32_32x32x16_bf16(A1[si], W1v, t2, 0, 0, 0);
                acc[nt] = t2;
            }

        if (t + 1 < 16) {
            // queue: [DMA(t+1)x3, A(t+1)x4] -> vmcnt(4) retires the DMAs
            asm volatile("s_waitcnt vmcnt(4)" ::: "memory");
            __builtin_amdgcn_s_barrier();
        }
    }

    // RACE FIX (R12 bug): drain all step-15 LDS reads before the combine
    // overlay reuses the staging region (overlay spans 33.7 KB > buf0).
    __syncthreads();

    // ---- combine K-halves via LDS overlay (now quiescent) ----
    if (kh == 1) {
        float* cA = (float*)smem + (size_t)(mg * 64 + lane) * 33;
#pragma unroll
        for (int nt = 0; nt < 2; ++nt)
#pragma unroll
            for (int q = 0; q < 16; ++q) cA[nt * 16 + q] = acc[nt][q];
    }
    __syncthreads();
    if (kh != 0) return;

    {
        const float* cA = (const float*)smem + (size_t)(mg * 64 + lane) * 33;
#pragma unroll
        for (int nt = 0; nt < 2; ++nt)
#pragma unroll
            for (int q = 0; q < 16; ++q) acc[nt][q] += cA[nt * 16 + q];
    }

    // C/D map: expert = nt*32 + col; token row = (q&3) + 8*(q>>2) + 4*hh.
    // ---- logits (per q: each 32-lane half writes 128B contiguous) ----
#pragma unroll
    for (int q = 0; q < 16; ++q) {
        const int row = (q & 3) + 8 * (q >> 2) + 4 * hh;
        float* lg = out + OFF_LOG + (size_t)(token0 + row) * NEXP + col;
        lg[0]  = acc[0][q];
        lg[32] = acc[1][q];
    }

    // ---- softmax + top-2 per token (32-lane halves, xor 1..16) ----
#pragma unroll
    for (int q = 0; q < 16; ++q) {
        const int token = token0 + (q & 3) + 8 * (q >> 2) + 4 * hh;
        float p0v = acc[0][q], p1v = acc[1][q];
        float mx = fmaxf(p0v, p1v);
#pragma unroll
        for (int d = 1; d <= 16; d <<= 1) mx = fmaxf(mx, __shfl_xor(mx, d, 64));

        float e0 = expf(p0v - mx);
        float e1 = expf(p1v - mx);
        float s = e0 + e1;
#pragma unroll
        for (int d = 1; d <= 16; d <<= 1) s += __shfl_xor(s, d, 64);

        // local top-2: experts col (nt=0) and 32+col (nt=1); lower idx wins ties
        float v1, v2; int i1, i2;
        if (e1 > e0) { v1 = e1; i1 = 32 + col; v2 = e0; i2 = col; }
        else         { v1 = e0; i1 = col;      v2 = e1; i2 = 32 + col; }

#pragma unroll
        for (int d = 1; d <= 16; d <<= 1) {
            float ov1 = __shfl_xor(v1, d, 64);
            float ov2 = __shfl_xor(v2, d, 64);
            int   oi1 = __shfl_xor(i1, d, 64);
            int   oi2 = __shfl_xor(i2, d, 64);
            bool ofirst = (ov1 > v1) || (ov1 == v1 && oi1 < i1);
            float n1, n2; int ni1, ni2;
            if (ofirst) {
                n1 = ov1; ni1 = oi1;
                bool sec = (v1 > ov2) || (v1 == ov2 && i1 < oi2);
                n2 = sec ? v1 : ov2; ni2 = sec ? i1 : oi2;
            } else {
                n1 = v1; ni1 = i1;
                bool sec = (ov1 > v2) || (ov1 == v2 && oi1 < i2);
                n2 = sec ? ov1 : v2; ni2 = sec ? oi1 : i2;
            }
            v1 = n1; i1 = ni1; v2 = n2; i2 = ni2;
        }

        if (col == 0) {
            float t1 = v1 / s;
            float t2 = v2 / s;
            float dn = t1 + t2 + 1e-8f;
            float2 pr; pr.x = t1 / dn; pr.y = t2 / dn;
            *reinterpret_cast<float2*>(out + (size_t)token * 2) = pr;
            float2 ex; ex.x = (float)i1; ex.y = (float)i2;
            *reinterpret_cast<float2*>(out + OFF_EXP + (size_t)token * 2) = ex;
        }
    }
#undef STAGE
}

extern "C" void kernel_launch(void* const* d_in, const int* in_sizes, int n_in,
                              void* d_out, int out_size, void* d_ws, size_t ws_size,
                              hipStream_t stream) {
    const float* h = (const float*)d_in[0];
    const float* w = (const float*)d_in[1];
    float* out = (float*)d_out;
    // d_ws: W1 | W2 | W3, each 65536 shorts = 384 KiB total
    short* w1 = (short*)d_ws;
    short* w2 = w1 + (size_t)NEXP * DDIM;
    short* w3 = w2 + (size_t)NEXP * DDIM;
    hipLaunchKernelGGL(w_split3_kernel, dim3(128), dim3(256), 0, stream, w, w1, w2, w3);
    hipLaunchKernelGGL(router_mfma_kernel, dim3(TOKENS / 128), dim3(512), 0, stream,
                       h, w1, w2, w3, out);
}